// Round 1
// baseline (1014.026 us; speedup 1.0000x reference)
//
#include <hip/hip_runtime.h>
#include <hip/hip_bf16.h>

#define NN 50000
#define NE 800000
#define KDIM 256      // IN = HC = 256
#define HCn 256
#define LATn 64

typedef short bf16x8 __attribute__((ext_vector_type(8)));
typedef float f32x4 __attribute__((ext_vector_type(4)));

__device__ __forceinline__ short f2b(float f) {
    __hip_bfloat16 h = __float2bfloat16(f);   // RNE
    return __builtin_bit_cast(short, h);
}
__device__ __forceinline__ float b2f(short s) {
    return __bfloat162float(__builtin_bit_cast(__hip_bfloat16, s));
}

// ---------------- CSR build ----------------
__global__ void hist_kernel(const int* __restrict__ dst, int* __restrict__ counts) {
    int e = blockIdx.x * 256 + threadIdx.x;
    if (e < NE) atomicAdd(&counts[dst[e]], 1);
}

__global__ void scan_kernel(const int* __restrict__ counts, int* __restrict__ offsets,
                            int* __restrict__ cursor) {
    __shared__ int part[256];
    const int t = threadIdx.x;
    const int chunk = (NN + 255) >> 8;   // 196
    int st = t * chunk, en = st + chunk; if (en > NN) en = NN;
    int s = 0;
    for (int k = st; k < en; ++k) s += counts[k];
    part[t] = s;
    __syncthreads();
    if (t == 0) {
        int c = 0;
        for (int q = 0; q < 256; ++q) { int v = part[q]; part[q] = c; c += v; }
        offsets[NN] = c;
    }
    __syncthreads();
    int run = part[t];
    for (int k = st; k < en; ++k) { offsets[k] = run; cursor[k] = run; run += counts[k]; }
}

__global__ void scatter_kernel(const int* __restrict__ src, const int* __restrict__ dst,
                               int* __restrict__ cursor, int* __restrict__ csr_src) {
    int e = blockIdx.x * 256 + threadIdx.x;
    if (e < NE) {
        int p = atomicAdd(&cursor[dst[e]], 1);
        csr_src[p] = src[e];
    }
}

// ---------------- GEMM: C[M,Nc] = A[M,256] @ W[256,Nc] (bf16 MFMA, f32 acc) ----------------
template<int A_BF16, int OUT_BF16, int ADD_BIAS>
__global__ __launch_bounds__(256) void gemm_k(
    const void* __restrict__ Ap, const float* __restrict__ W,
    void* __restrict__ Outp, const float* __restrict__ bias, int M, int Nc)
{
    __shared__ short As[64 * 40];   // 64 rows x 32 k (stride 40 to dodge bank conflicts)
    __shared__ short Bs[64 * 40];   // 64 cols x 32 k (transposed W tile)
    const int t = threadIdx.x;
    const int row0 = blockIdx.x * 64;
    const int col0 = blockIdx.y * 64;
    const int w = t >> 6, lane = t & 63;
    f32x4 acc[4];
#pragma unroll
    for (int i = 0; i < 4; ++i) acc[i] = (f32x4){0.f, 0.f, 0.f, 0.f};

    const int ar = t >> 2, ac0 = (t & 3) * 8;   // A staging: 4 thr/row, 8 elems each
    const int bk = t >> 3, bn0 = (t & 7) * 8;   // B staging: 8 thr/k-row, 8 cols each
    const int arow = lane & 15, kq = lane >> 4;

    for (int k0 = 0; k0 < KDIM; k0 += 32) {
        // stage A (64x32)
        {
            short tmp[8];
            int gr = row0 + ar;
            if (gr < M) {
                if (A_BF16) {
                    const short* A = (const short*)Ap;
                    bf16x8 v = *reinterpret_cast<const bf16x8*>(A + (long)gr * KDIM + k0 + ac0);
#pragma unroll
                    for (int j = 0; j < 8; ++j) tmp[j] = v[j];
                } else {
                    const float* A = (const float*)Ap;
                    const f32x4* p = reinterpret_cast<const f32x4*>(A + (long)gr * KDIM + k0 + ac0);
                    f32x4 v0 = p[0], v1 = p[1];
#pragma unroll
                    for (int j = 0; j < 4; ++j) { tmp[j] = f2b(v0[j]); tmp[4 + j] = f2b(v1[j]); }
                }
            } else {
#pragma unroll
                for (int j = 0; j < 8; ++j) tmp[j] = 0;
            }
            bf16x8 sv;
#pragma unroll
            for (int j = 0; j < 8; ++j) sv[j] = tmp[j];
            *reinterpret_cast<bf16x8*>(&As[ar * 40 + ac0]) = sv;
        }
        // stage B transposed: Bs[n][k] = W[k0+k][col0+n]
        {
            const float* wp = W + (long)(k0 + bk) * Nc + col0 + bn0;
            f32x4 v0 = *reinterpret_cast<const f32x4*>(wp);
            f32x4 v1 = *reinterpret_cast<const f32x4*>(wp + 4);
#pragma unroll
            for (int j = 0; j < 4; ++j) {
                Bs[(bn0 + j) * 40 + bk]     = f2b(v0[j]);
                Bs[(bn0 + 4 + j) * 40 + bk] = f2b(v1[j]);
            }
        }
        __syncthreads();
        bf16x8 a = *reinterpret_cast<const bf16x8*>(&As[(w * 16 + arow) * 40 + kq * 8]);
#pragma unroll
        for (int nt = 0; nt < 4; ++nt) {
            bf16x8 b = *reinterpret_cast<const bf16x8*>(&Bs[(nt * 16 + arow) * 40 + kq * 8]);
            acc[nt] = __builtin_amdgcn_mfma_f32_16x16x32_bf16(a, b, acc[nt], 0, 0, 0);
        }
        __syncthreads();
    }
    // epilogue: C/D layout col=lane&15, row=(lane>>4)*4+r (m89-verified)
#pragma unroll
    for (int nt = 0; nt < 4; ++nt) {
        int gc = col0 + nt * 16 + (lane & 15);
#pragma unroll
        for (int r = 0; r < 4; ++r) {
            int gr = row0 + w * 16 + (lane >> 4) * 4 + r;
            if (gr < M) {
                float v = acc[nt][r];
                if (ADD_BIAS) v += bias[gc];
                if (OUT_BF16) ((short*)Outp)[(long)gr * Nc + gc] = f2b(v);
                else          ((float*)Outp)[(long)gr * Nc + gc] = v;
            }
        }
    }
}

// ---------------- fused GATv2 gather + softmax + aggregate + bias + LN + ELU ----------------
// one block per dst node; 256 thr = 4 waves = 4 heads; lane = channel
__global__ __launch_bounds__(256) void gat_node_kernel(
    const short* __restrict__ xl, const short* __restrict__ xr,
    const int* __restrict__ offsets, const int* __restrict__ csr_src,
    const float* __restrict__ att, const float* __restrict__ bias,
    const float* __restrict__ ln_g, const float* __restrict__ ln_b,
    short* __restrict__ hout)
{
    const int i = blockIdx.x;
    const int t = threadIdx.x;
    const int lane = t & 63;
    const int w = t >> 6;

    const float att_t = att[t];
    const float xr_t  = b2f(xr[(long)i * HCn + t]);

    float m = -3e38f, l = 0.f, acc = 0.f;
    const int p0 = offsets[i], p1 = offsets[i + 1];
    // p = p0-1 is the implicit self loop (src = i)
    for (int p = p0 - 1; p < p1; ++p) {
        int j = (p < p0) ? i : csr_src[p];
        float xl_t = b2f(xl[(long)j * HCn + t]);
        float val = xl_t + xr_t;
        val = val > 0.f ? val : 0.2f * val;          // leaky_relu(0.2)
        float s = val * att_t;
#pragma unroll
        for (int off = 32; off; off >>= 1) s += __shfl_xor(s, off, 64);
        float mn = fmaxf(m, s);
        float corr = __expf(m - mn);
        float ex   = __expf(s - mn);
        acc = acc * corr + ex * xl_t;
        l   = l * corr + ex;
        m = mn;
    }
    float out = acc / l + bias[t];

    // LayerNorm over 256 channels + ELU
    float s1 = out, s2 = out * out;
#pragma unroll
    for (int off = 32; off; off >>= 1) {
        s1 += __shfl_xor(s1, off, 64);
        s2 += __shfl_xor(s2, off, 64);
    }
    __shared__ float red[8];
    if (lane == 0) { red[w] = s1; red[4 + w] = s2; }
    __syncthreads();
    s1 = red[0] + red[1] + red[2] + red[3];
    s2 = red[4] + red[5] + red[6] + red[7];
    float mu  = s1 * (1.f / HCn);
    float var = s2 * (1.f / HCn) - mu * mu;
    float y = (out - mu) * rsqrtf(var + 1e-5f) * ln_g[t] + ln_b[t];
    y = y > 0.f ? y : expm1f(y);                     // ELU(alpha=1)
    hout[(long)i * HCn + t] = f2b(y);
}

// ---------------- launch ----------------
extern "C" void kernel_launch(void* const* d_in, const int* in_sizes, int n_in,
                              void* d_out, int out_size, void* d_ws, size_t ws_size,
                              hipStream_t stream) {
    const float* x    = (const float*)d_in[0];
    const int*   ei   = (const int*)d_in[1];
    const float* Wl1  = (const float*)d_in[2];
    const float* Wr1  = (const float*)d_in[3];
    const float* att1 = (const float*)d_in[4];
    const float* b1   = (const float*)d_in[5];
    const float* ln1g = (const float*)d_in[6];
    const float* ln1b = (const float*)d_in[7];
    const float* Wl2  = (const float*)d_in[8];
    const float* Wr2  = (const float*)d_in[9];
    const float* att2 = (const float*)d_in[10];
    const float* b2   = (const float*)d_in[11];
    const float* ln2g = (const float*)d_in[12];
    const float* ln2b = (const float*)d_in[13];
    const float* Wmu  = (const float*)d_in[14];
    const float* bmu  = (const float*)d_in[15];
    const float* Wlv  = (const float*)d_in[16];
    const float* blv  = (const float*)d_in[17];
    float* out = (float*)d_out;

    // workspace layout (~80.5 MB)
    short* buf0 = (short*)d_ws;                 // xl  [N,256] bf16
    short* buf1 = buf0 + (long)NN * HCn;        // xr  [N,256] bf16
    short* buf2 = buf1 + (long)NN * HCn;        // h   [N,256] bf16
    int* counts  = (int*)(buf2 + (long)NN * HCn);
    int* offsets = counts + NN;                 // N+1
    int* cursor  = offsets + NN + 1;
    int* csr_src = cursor + NN;                 // E

    const int* src = ei;
    const int* dst = ei + NE;

    // CSR by dst (self loops handled implicitly in gat_node_kernel)
    hipMemsetAsync(counts, 0, NN * sizeof(int), stream);
    hist_kernel<<<(NE + 255) / 256, 256, 0, stream>>>(dst, counts);
    scan_kernel<<<1, 256, 0, stream>>>(counts, offsets, cursor);
    scatter_kernel<<<(NE + 255) / 256, 256, 0, stream>>>(src, dst, cursor, csr_src);

    const int GM = (NN + 63) / 64;   // 782
    dim3 gbig(GM, HCn / 64);         // 782 x 4
    dim3 gsml(GM, LATn / 64);        // 782 x 1

    // layer 1
    gemm_k<0, 1, 0><<<gbig, 256, 0, stream>>>(x, Wl1, buf0, nullptr, NN, HCn);
    gemm_k<0, 1, 0><<<gbig, 256, 0, stream>>>(x, Wr1, buf1, nullptr, NN, HCn);
    gat_node_kernel<<<NN, 256, 0, stream>>>(buf0, buf1, offsets, csr_src,
                                            att1, b1, ln1g, ln1b, buf2);
    // layer 2
    gemm_k<1, 1, 0><<<gbig, 256, 0, stream>>>(buf2, Wl2, buf0, nullptr, NN, HCn);
    gemm_k<1, 1, 0><<<gbig, 256, 0, stream>>>(buf2, Wr2, buf1, nullptr, NN, HCn);
    gat_node_kernel<<<NN, 256, 0, stream>>>(buf0, buf1, offsets, csr_src,
                                            att2, b2, ln2g, ln2b, buf2);
    // heads
    gemm_k<1, 0, 1><<<gsml, 256, 0, stream>>>(buf2, Wmu, out,                 bmu, NN, LATn);
    gemm_k<1, 0, 1><<<gsml, 256, 0, stream>>>(buf2, Wlv, out + (long)NN * LATn, blv, NN, LATn);
}

// Round 2
// 579.389 us; speedup vs baseline: 1.7502x; 1.7502x over previous
//
#include <hip/hip_runtime.h>
#include <hip/hip_bf16.h>

#define NN 50000
#define NE 800000
#define HCn 256
#define LATn 64

typedef short bf16x4 __attribute__((ext_vector_type(4)));
typedef short bf16x8 __attribute__((ext_vector_type(8)));
typedef float f32x4 __attribute__((ext_vector_type(4)));

__device__ __forceinline__ short f2b(float f) {
    __hip_bfloat16 h = __float2bfloat16(f);   // RNE
    return __builtin_bit_cast(short, h);
}
__device__ __forceinline__ float b2f(short s) {
    return __bfloat162float(__builtin_bit_cast(__hip_bfloat16, s));
}

// ---------------- CSR build ----------------
__global__ void hist_kernel(const int* __restrict__ dst, int* __restrict__ counts) {
    int e = blockIdx.x * 256 + threadIdx.x;
    if (e < NE) atomicAdd(&counts[dst[e]], 1);
}

__global__ void scan_kernel(const int* __restrict__ counts, int* __restrict__ offsets,
                            int* __restrict__ cursor) {
    __shared__ int part[256];
    const int t = threadIdx.x;
    const int chunk = (NN + 255) >> 8;   // 196
    int st = t * chunk, en = st + chunk; if (en > NN) en = NN;
    int s = 0;
    for (int k = st; k < en; ++k) s += counts[k];
    part[t] = s;
    __syncthreads();
    if (t == 0) {
        int c = 0;
        for (int q = 0; q < 256; ++q) { int v = part[q]; part[q] = c; c += v; }
        offsets[NN] = c;
    }
    __syncthreads();
    int run = part[t];
    for (int k = st; k < en; ++k) { offsets[k] = run; cursor[k] = run; run += counts[k]; }
}

__global__ void scatter_kernel(const int* __restrict__ src, const int* __restrict__ dst,
                               int* __restrict__ cursor, int* __restrict__ csr_src) {
    int e = blockIdx.x * 256 + threadIdx.x;
    if (e < NE) {
        int p = atomicAdd(&cursor[dst[e]], 1);
        csr_src[p] = src[e];
    }
}

// ---------------- f32 -> bf16 convert (x) ----------------
__global__ __launch_bounds__(256) void cvt_x_kernel(const float* __restrict__ x,
                                                    short* __restrict__ xb) {
    long i = ((long)blockIdx.x * 256 + threadIdx.x) * 8;
    const f32x4* p = reinterpret_cast<const f32x4*>(x + i);
    f32x4 a = p[0], b = p[1];
    bf16x8 o;
#pragma unroll
    for (int j = 0; j < 4; ++j) { o[j] = f2b(a[j]); o[4 + j] = f2b(b[j]); }
    *reinterpret_cast<bf16x8*>(xb + i) = o;
}

// ---------------- pack weights to bf16: Wb1=[Wl1|Wr1], Wb2=[Wl2|Wr2], Wb3=[Wmu|Wlv] ----------------
__global__ void pack_w_kernel(const float* __restrict__ Wl1, const float* __restrict__ Wr1,
                              const float* __restrict__ Wl2, const float* __restrict__ Wr2,
                              const float* __restrict__ Wmu, const float* __restrict__ Wlv,
                              const float* __restrict__ bmu, const float* __restrict__ blv,
                              short* __restrict__ Wb1, short* __restrict__ Wb2,
                              short* __restrict__ Wb3, float* __restrict__ bias3) {
    int i = blockIdx.x * 256 + threadIdx.x;
    const int S1 = 256 * 512, S2 = 2 * S1, S3 = S2 + 256 * 128;
    if (i < S1) {
        int k = i >> 9, c = i & 511;
        float v = (c < 256) ? Wl1[k * 256 + c] : Wr1[k * 256 + (c - 256)];
        Wb1[i] = f2b(v);
    } else if (i < S2) {
        int j = i - S1; int k = j >> 9, c = j & 511;
        float v = (c < 256) ? Wl2[k * 256 + c] : Wr2[k * 256 + (c - 256)];
        Wb2[j] = f2b(v);
    } else if (i < S3) {
        int j = i - S2; int k = j >> 7, c = j & 127;
        float v = (c < 64) ? Wmu[k * 64 + c] : Wlv[k * 64 + (c - 64)];
        Wb3[j] = f2b(v);
    } else if (i < S3 + 128) {
        int c = i - S3;
        bias3[c] = (c < 64) ? bmu[c] : blv[c - 64];
    }
}

// ---------------- GEMM: out[M,Nc] = A[M,256] @ Wb[256,Nc], bf16 MFMA ----------------
// 128x64 tile, 4 waves (wave = 32 rows), B panel staged ONCE in LDS, A frags direct from global.
template<int OUT_MODE>   // 0: bf16 out, row-stride Nc | 1: f32 out split 64|64 + bias
__global__ __launch_bounds__(256) void gemm_k(
    const short* __restrict__ A, const short* __restrict__ Wb,
    void* __restrict__ outp, const float* __restrict__ bias, int Nc)
{
    __shared__ short Bs[64 * 264];   // [n][k], stride 264 (2-way-free ds_read_b128)
    const int t = threadIdx.x;
    const int w = t >> 6, lane = t & 63;
    const int row0 = blockIdx.x * 128, col0 = blockIdx.y * 64;

    // stage B panel once: Bs[n][k] = Wb[k][col0+n]
    {
        const int kb = t >> 3, n0 = (t & 7) * 8;
#pragma unroll
        for (int r = 0; r < 8; ++r) {
            int k = r * 32 + kb;
            bf16x8 v = *reinterpret_cast<const bf16x8*>(Wb + (long)k * Nc + col0 + n0);
#pragma unroll
            for (int j = 0; j < 8; ++j) Bs[(n0 + j) * 264 + k] = v[j];
        }
    }
    __syncthreads();

    f32x4 acc[2][4];
#pragma unroll
    for (int a = 0; a < 2; ++a)
#pragma unroll
        for (int b = 0; b < 4; ++b) acc[a][b] = (f32x4){0.f, 0.f, 0.f, 0.f};

    const int arow = lane & 15, kq = lane >> 4;
    int r0 = row0 + w * 32 + arow;      if (r0 > NN - 1) r0 = NN - 1;
    int r1 = row0 + w * 32 + 16 + arow; if (r1 > NN - 1) r1 = NN - 1;
    const short* pa0 = A + (long)r0 * 256 + kq * 8;
    const short* pa1 = A + (long)r1 * 256 + kq * 8;

#pragma unroll
    for (int k0 = 0; k0 < 256; k0 += 32) {
        bf16x8 a0 = *reinterpret_cast<const bf16x8*>(pa0 + k0);
        bf16x8 a1 = *reinterpret_cast<const bf16x8*>(pa1 + k0);
#pragma unroll
        for (int nt = 0; nt < 4; ++nt) {
            bf16x8 b = *reinterpret_cast<const bf16x8*>(&Bs[(nt * 16 + arow) * 264 + k0 + kq * 8]);
            acc[0][nt] = __builtin_amdgcn_mfma_f32_16x16x32_bf16(a0, b, acc[0][nt], 0, 0, 0);
            acc[1][nt] = __builtin_amdgcn_mfma_f32_16x16x32_bf16(a1, b, acc[1][nt], 0, 0, 0);
        }
    }

    // epilogue: C/D layout col = lane&15, row = (lane>>4)*4 + r
#pragma unroll
    for (int rb = 0; rb < 2; ++rb)
#pragma unroll
        for (int nt = 0; nt < 4; ++nt) {
            int gcol = col0 + nt * 16 + arow;
#pragma unroll
            for (int r = 0; r < 4; ++r) {
                int grow = row0 + w * 32 + rb * 16 + kq * 4 + r;
                if (grow < NN) {
                    float v = acc[rb][nt][r];
                    if (OUT_MODE == 0) {
                        ((short*)outp)[(long)grow * Nc + gcol] = f2b(v);
                    } else {
                        v += bias[gcol];
                        float* o = (float*)outp;
                        if (gcol < 64) o[(long)grow * 64 + gcol] = v;
                        else           o[(long)NN * 64 + (long)grow * 64 + (gcol - 64)] = v;
                    }
                }
            }
        }
}

// ---------------- fused GATv2: one WAVE per node, 4x16-lane head groups ----------------
// xlr: [N,512] bf16 (cols 0..255 = xl = Wl h, cols 256..511 = xr = Wr h)
__global__ __launch_bounds__(256) void gat_node_kernel(
    const short* __restrict__ xlr,
    const int* __restrict__ offsets, const int* __restrict__ csr_src,
    const float* __restrict__ att, const float* __restrict__ bias,
    const float* __restrict__ ln_g, const float* __restrict__ ln_b,
    short* __restrict__ hout)
{
    const int i = blockIdx.x * 4 + (threadIdx.x >> 6);
    const int lane = threadIdx.x & 63;
    const int c4 = (lane >> 4) * 64 + (lane & 15) * 4;   // head*(C=64) + 4 channels

    f32x4 attv = *reinterpret_cast<const f32x4*>(att + c4);
    float xr[4];
    {
        bf16x4 v = *reinterpret_cast<const bf16x4*>(xlr + (long)i * 512 + 256 + c4);
#pragma unroll
        for (int k = 0; k < 4; ++k) xr[k] = b2f(v[k]);
    }

    float m = -3e38f, l = 0.f;
    float acc[4] = {0.f, 0.f, 0.f, 0.f};
    const int p0 = offsets[i], p1 = offsets[i + 1];

    for (int p = p0 - 1; p < p1; ++p) {
        int j = (p < p0) ? i : csr_src[p];
        j = __builtin_amdgcn_readfirstlane(j);          // wave-uniform -> scalar addressing
        bf16x4 v = *reinterpret_cast<const bf16x4*>(xlr + (long)j * 512 + c4);
        float xf[4], s = 0.f;
#pragma unroll
        for (int k = 0; k < 4; ++k) {
            xf[k] = b2f(v[k]);
            float val = xf[k] + xr[k];
            val = fmaxf(val, 0.2f * val);               // leaky_relu(0.2)
            s = fmaf(val, attv[k], s);
        }
        // 16-lane group reduce (per-head score); xor<16 stays within group
        s += __shfl_xor(s, 1, 64);
        s += __shfl_xor(s, 2, 64);
        s += __shfl_xor(s, 4, 64);
        s += __shfl_xor(s, 8, 64);
        float mn = fmaxf(m, s);
        float corr = __expf(m - mn);
        float ex   = __expf(s - mn);
        l = fmaf(l, corr, ex);
#pragma unroll
        for (int k = 0; k < 4; ++k) acc[k] = fmaf(acc[k], corr, ex * xf[k]);
        m = mn;
    }

    float inv = 1.f / l;
    f32x4 bv = *reinterpret_cast<const f32x4*>(bias + c4);
    float out[4], s1 = 0.f, s2 = 0.f;
#pragma unroll
    for (int k = 0; k < 4; ++k) {
        out[k] = acc[k] * inv + bv[k];
        s1 += out[k];
        s2 += out[k] * out[k];
    }
    // LN over 256 channels: full-wave butterfly
#pragma unroll
    for (int off = 1; off < 64; off <<= 1) {
        s1 += __shfl_xor(s1, off, 64);
        s2 += __shfl_xor(s2, off, 64);
    }
    float mu  = s1 * (1.f / 256.f);
    float var = s2 * (1.f / 256.f) - mu * mu;
    float rs  = rsqrtf(var + 1e-5f);
    f32x4 gv  = *reinterpret_cast<const f32x4*>(ln_g + c4);
    f32x4 bbv = *reinterpret_cast<const f32x4*>(ln_b + c4);
    bf16x4 o;
#pragma unroll
    for (int k = 0; k < 4; ++k) {
        float y = (out[k] - mu) * rs * gv[k] + bbv[k];
        y = y > 0.f ? y : expm1f(y);                    // ELU
        o[k] = f2b(y);
    }
    *reinterpret_cast<bf16x4*>(hout + (long)i * 256 + c4) = o;
}

// ---------------- launch ----------------
extern "C" void kernel_launch(void* const* d_in, const int* in_sizes, int n_in,
                              void* d_out, int out_size, void* d_ws, size_t ws_size,
                              hipStream_t stream) {
    const float* x    = (const float*)d_in[0];
    const int*   ei   = (const int*)d_in[1];
    const float* Wl1  = (const float*)d_in[2];
    const float* Wr1  = (const float*)d_in[3];
    const float* att1 = (const float*)d_in[4];
    const float* b1   = (const float*)d_in[5];
    const float* ln1g = (const float*)d_in[6];
    const float* ln1b = (const float*)d_in[7];
    const float* Wl2  = (const float*)d_in[8];
    const float* Wr2  = (const float*)d_in[9];
    const float* att2 = (const float*)d_in[10];
    const float* b2   = (const float*)d_in[11];
    const float* ln2g = (const float*)d_in[12];
    const float* ln2b = (const float*)d_in[13];
    const float* Wmu  = (const float*)d_in[14];
    const float* bmu  = (const float*)d_in[15];
    const float* Wlv  = (const float*)d_in[16];
    const float* blv  = (const float*)d_in[17];

    // workspace layout
    short* bufXL = (short*)d_ws;                       // [N,512] bf16 (xl|xr)
    short* bufH  = bufXL + (long)NN * 512;             // [N,256] bf16 (also xb before gemm1)
    short* Wb1   = bufH + (long)NN * 256;              // 256*512
    short* Wb2   = Wb1 + 256 * 512;
    short* Wb3   = Wb2 + 256 * 512;                    // 256*128
    float* bias3 = (float*)(Wb3 + 256 * 128);          // 128
    int* counts  = (int*)(bias3 + 128);
    int* offsets = counts + NN;                        // N+1
    int* cursor  = offsets + NN + 1;
    int* csr_src = cursor + NN;                        // E

    const int* src = ei;
    const int* dst = ei + NE;

    // CSR by dst
    hipMemsetAsync(counts, 0, NN * sizeof(int), stream);
    hist_kernel<<<(NE + 255) / 256, 256, 0, stream>>>(dst, counts);
    scan_kernel<<<1, 256, 0, stream>>>(counts, offsets, cursor);
    scatter_kernel<<<(NE + 255) / 256, 256, 0, stream>>>(src, dst, cursor, csr_src);

    // prep: x -> bf16 (into bufH region), pack weights
    cvt_x_kernel<<<(NN * HCn) / (8 * 256), 256, 0, stream>>>(x, bufH);
    pack_w_kernel<<<1153, 256, 0, stream>>>(Wl1, Wr1, Wl2, Wr2, Wmu, Wlv, bmu, blv,
                                            Wb1, Wb2, Wb3, bias3);

    const int GM = (NN + 127) / 128;   // 391
    dim3 g1(GM, 8);                    // Nc=512
    dim3 g3(GM, 2);                    // Nc=128

    // layer 1
    gemm_k<0><<<g1, 256, 0, stream>>>(bufH, Wb1, bufXL, nullptr, 512);
    gat_node_kernel<<<NN / 4, 256, 0, stream>>>(bufXL, offsets, csr_src,
                                                att1, b1, ln1g, ln1b, bufH);
    // layer 2
    gemm_k<0><<<g1, 256, 0, stream>>>(bufH, Wb2, bufXL, nullptr, 512);
    gat_node_kernel<<<NN / 4, 256, 0, stream>>>(bufXL, offsets, csr_src,
                                                att2, b2, ln2g, ln2b, bufH);
    // heads: [mu|logvar]
    gemm_k<1><<<g3, 256, 0, stream>>>(bufH, Wb3, d_out, bias3, 128);
}

// Round 4
// 498.922 us; speedup vs baseline: 2.0324x; 1.1613x over previous
//
#include <hip/hip_runtime.h>
#include <hip/hip_bf16.h>

#define NN 50000
#define NE 800000
#define HCn 256
#define LATn 64

typedef short bf16x4 __attribute__((ext_vector_type(4)));
typedef short bf16x8 __attribute__((ext_vector_type(8)));
typedef float f32x4 __attribute__((ext_vector_type(4)));

__device__ __forceinline__ short f2b(float f) {
    __hip_bfloat16 h = __float2bfloat16(f);   // RNE
    return __builtin_bit_cast(short, h);
}
__device__ __forceinline__ float b2f(short s) {
    return __bfloat162float(__builtin_bit_cast(__hip_bfloat16, s));
}

// single-instruction lane swizzle (BitMode xor; works within 32-lane halves)
#define SWZF(v, pat) __builtin_bit_cast(float, __builtin_amdgcn_ds_swizzle(__builtin_bit_cast(int, v), pat))

// ---------------- CSR build ----------------
__global__ void hist_kernel(const int* __restrict__ dst, int* __restrict__ counts) {
    int e = blockIdx.x * 256 + threadIdx.x;
    if (e < NE) atomicAdd(&counts[dst[e]], 1);
}

__global__ void scan_kernel(const int* __restrict__ counts, int* __restrict__ offsets,
                            int* __restrict__ cursor) {
    __shared__ int part[256];
    const int t = threadIdx.x;
    const int chunk = (NN + 255) >> 8;   // 196
    int st = t * chunk, en = st + chunk; if (en > NN) en = NN;
    int s = 0;
    for (int k = st; k < en; ++k) s += counts[k];
    part[t] = s;
    __syncthreads();
    if (t == 0) {
        int c = 0;
        for (int q = 0; q < 256; ++q) { int v = part[q]; part[q] = c; c += v; }
        offsets[NN] = c;
    }
    __syncthreads();
    int run = part[t];
    for (int k = st; k < en; ++k) { offsets[k] = run; cursor[k] = run; run += counts[k]; }
}

__global__ void scatter_kernel(const int* __restrict__ src, const int* __restrict__ dst,
                               int* __restrict__ cursor, int* __restrict__ csr_src) {
    int e = blockIdx.x * 256 + threadIdx.x;
    if (e < NE) {
        int p = atomicAdd(&cursor[dst[e]], 1);
        csr_src[p] = src[e];
    }
}

// ---------------- f32 -> bf16 convert (x) ----------------
__global__ __launch_bounds__(256) void cvt_x_kernel(const float* __restrict__ x,
                                                    short* __restrict__ xb) {
    long i = ((long)blockIdx.x * 256 + threadIdx.x) * 8;
    const f32x4* p = reinterpret_cast<const f32x4*>(x + i);
    f32x4 a = p[0], b = p[1];
    bf16x8 o;
#pragma unroll
    for (int j = 0; j < 4; ++j) { o[j] = f2b(a[j]); o[4 + j] = f2b(b[j]); }
    *reinterpret_cast<bf16x8*>(xb + i) = o;
}

// ---------------- pack weights to bf16, TRANSPOSED: Wbt[n][k] = W[k][n] ----------------
__global__ void pack_w_kernel(const float* __restrict__ Wl1, const float* __restrict__ Wr1,
                              const float* __restrict__ Wl2, const float* __restrict__ Wr2,
                              const float* __restrict__ Wmu, const float* __restrict__ Wlv,
                              const float* __restrict__ bmu, const float* __restrict__ blv,
                              short* __restrict__ Wb1t, short* __restrict__ Wb2t,
                              short* __restrict__ Wb3t, float* __restrict__ bias3) {
    int i = blockIdx.x * 256 + threadIdx.x;
    const int S1 = 512 * 256, S2 = 2 * S1, S3 = S2 + 128 * 256;
    if (i < S1) {
        int c = i >> 8, k = i & 255;
        float v = (c < 256) ? Wl1[k * 256 + c] : Wr1[k * 256 + (c - 256)];
        Wb1t[i] = f2b(v);
    } else if (i < S2) {
        int j = i - S1; int c = j >> 8, k = j & 255;
        float v = (c < 256) ? Wl2[k * 256 + c] : Wr2[k * 256 + (c - 256)];
        Wb2t[j] = f2b(v);
    } else if (i < S3) {
        int j = i - S2; int c = j >> 8, k = j & 255;
        float v = (c < 64) ? Wmu[k * 64 + c] : Wlv[k * 64 + (c - 64)];
        Wb3t[j] = f2b(v);
    } else if (i < S3 + 128) {
        int c = i - S3;
        bias3[c] = (c < 64) ? bmu[c] : blv[c - 64];
    }
}

// ---------------- GEMM: out[M,Nc] = A[M,256] @ W[256,Nc], W given transposed Wbt[Nc,256] ----------------
// 128x64 tile, 4 waves; B panel staged once in LDS via b128 writes; A frags direct from global.
template<int OUT_MODE>   // 0: bf16 out, row-stride Nc | 1: f32 out split 64|64 + bias
__global__ __launch_bounds__(256) void gemm_k(
    const short* __restrict__ A, const short* __restrict__ Wbt,
    void* __restrict__ outp, const float* __restrict__ bias, int Nc)
{
    __shared__ short Bs[64 * 264];   // [n][k], stride 264
    const int t = threadIdx.x;
    const int w = t >> 6, lane = t & 63;
    const int row0 = blockIdx.x * 128, col0 = blockIdx.y * 64;

    // stage B panel once: Bs[n][k] = Wbt[col0+n][k]  (coalesced load, b128 LDS write)
    {
        const int sn = t >> 2;            // 0..63
        const int sk0 = (t & 3) * 8;      // 0,8,16,24
        const short* wp = Wbt + (long)(col0 + sn) * 256 + sk0;
#pragma unroll
        for (int r = 0; r < 8; ++r) {
            int k = r * 32 + sk0;
            bf16x8 v = *reinterpret_cast<const bf16x8*>(wp + r * 32);
            *reinterpret_cast<bf16x8*>(&Bs[sn * 264 + k]) = v;
        }
    }
    __syncthreads();

    f32x4 acc[2][4];
#pragma unroll
    for (int a = 0; a < 2; ++a)
#pragma unroll
        for (int b = 0; b < 4; ++b) acc[a][b] = (f32x4){0.f, 0.f, 0.f, 0.f};

    const int arow = lane & 15, kq = lane >> 4;
    int r0 = row0 + w * 32 + arow;      if (r0 > NN - 1) r0 = NN - 1;
    int r1 = row0 + w * 32 + 16 + arow; if (r1 > NN - 1) r1 = NN - 1;
    const short* pa0 = A + (long)r0 * 256 + kq * 8;
    const short* pa1 = A + (long)r1 * 256 + kq * 8;

#pragma unroll
    for (int k0 = 0; k0 < 256; k0 += 32) {
        bf16x8 a0 = *reinterpret_cast<const bf16x8*>(pa0 + k0);
        bf16x8 a1 = *reinterpret_cast<const bf16x8*>(pa1 + k0);
#pragma unroll
        for (int nt = 0; nt < 4; ++nt) {
            bf16x8 b = *reinterpret_cast<const bf16x8*>(&Bs[(nt * 16 + arow) * 264 + k0 + kq * 8]);
            acc[0][nt] = __builtin_amdgcn_mfma_f32_16x16x32_bf16(a0, b, acc[0][nt], 0, 0, 0);
            acc[1][nt] = __builtin_amdgcn_mfma_f32_16x16x32_bf16(a1, b, acc[1][nt], 0, 0, 0);
        }
    }

    // epilogue: C/D layout col = lane&15, row = (lane>>4)*4 + r
#pragma unroll
    for (int rb = 0; rb < 2; ++rb)
#pragma unroll
        for (int nt = 0; nt < 4; ++nt) {
            int gcol = col0 + nt * 16 + arow;
#pragma unroll
            for (int r = 0; r < 4; ++r) {
                int grow = row0 + w * 32 + rb * 16 + kq * 4 + r;
                if (grow < NN) {
                    float v = acc[rb][nt][r];
                    if (OUT_MODE == 0) {
                        ((short*)outp)[(long)grow * Nc + gcol] = f2b(v);
                    } else {
                        v += bias[gcol];
                        float* o = (float*)outp;
                        if (gcol < 64) o[(long)grow * 64 + gcol] = v;
                        else           o[(long)NN * 64 + (long)grow * 64 + (gcol - 64)] = v;
                    }
                }
            }
        }
}

// ---------------- fused GATv2: one WAVE per node, 4x16-lane head groups ----------------
// xlr: [N,512] bf16 (cols 0..255 = xl, cols 256..511 = xr)
__device__ __forceinline__ void edge_score(const short* __restrict__ xlr, int j, int c4,
                                           const float* xr, const f32x4& attv,
                                           float* xf, float& s) {
    bf16x4 v = *reinterpret_cast<const bf16x4*>(xlr + (long)j * 512 + c4);
    s = 0.f;
#pragma unroll
    for (int k = 0; k < 4; ++k) {
        xf[k] = b2f(v[k]);
        float val = xf[k] + xr[k];
        val = fmaxf(val, 0.2f * val);               // leaky_relu(0.2)
        s = fmaf(val, attv[k], s);
    }
    // 16-lane head-group reduce: xor 1,2,4,8
    s += SWZF(s, 0x041F);
    s += SWZF(s, 0x081F);
    s += SWZF(s, 0x101F);
    s += SWZF(s, 0x201F);
}

__global__ __launch_bounds__(256) void gat_node_kernel(
    const short* __restrict__ xlr,
    const int* __restrict__ offsets, const int* __restrict__ csr_src,
    const float* __restrict__ att, const float* __restrict__ bias,
    const float* __restrict__ ln_g, const float* __restrict__ ln_b,
    short* __restrict__ hout)
{
    const int i = blockIdx.x * 4 + (threadIdx.x >> 6);
    const int lane = threadIdx.x & 63;
    const int c4 = (lane >> 4) * 64 + (lane & 15) * 4;   // head*64 + 4 channels

    f32x4 attv = *reinterpret_cast<const f32x4*>(att + c4);
    float xr[4];
    {
        bf16x4 v = *reinterpret_cast<const bf16x4*>(xlr + (long)i * 512 + 256 + c4);
#pragma unroll
        for (int k = 0; k < 4; ++k) xr[k] = b2f(v[k]);
    }

    float m, l;
    float acc[4];
    // self loop first: alpha-unnorm = 1, m = s_self
    {
        float xf[4], s;
        edge_score(xlr, i, c4, xr, attv, xf, s);
        m = s; l = 1.f;
#pragma unroll
        for (int k = 0; k < 4; ++k) acc[k] = xf[k];
    }

    const int p0 = offsets[i], p1 = offsets[i + 1];
    int p = p0;
    for (; p + 2 <= p1; p += 2) {
        int ja = __builtin_amdgcn_readfirstlane(csr_src[p]);
        int jb = __builtin_amdgcn_readfirstlane(csr_src[p + 1]);
        float xa[4], xb[4], sa, sb;
        edge_score(xlr, ja, c4, xr, attv, xa, sa);
        edge_score(xlr, jb, c4, xr, attv, xb, sb);
        float sm = fmaxf(sa, sb);
        if (__all(sm <= m + 4.f)) {
            // defer-max: keep m, no rescale (values bounded by e^4)
            float exa = __expf(sa - m), exb = __expf(sb - m);
            l += exa + exb;
#pragma unroll
            for (int k = 0; k < 4; ++k)
                acc[k] += exa * xa[k] + exb * xb[k];
        } else {
            float mn = fmaxf(m, sm);
            float corr = __expf(m - mn);
            float exa = __expf(sa - mn), exb = __expf(sb - mn);
            l = fmaf(l, corr, exa + exb);
#pragma unroll
            for (int k = 0; k < 4; ++k)
                acc[k] = fmaf(acc[k], corr, exa * xa[k] + exb * xb[k]);
            m = mn;
        }
    }
    if (p < p1) {
        int ja = __builtin_amdgcn_readfirstlane(csr_src[p]);
        float xa[4], sa;
        edge_score(xlr, ja, c4, xr, attv, xa, sa);
        if (__all(sa <= m + 4.f)) {
            float exa = __expf(sa - m);
            l += exa;
#pragma unroll
            for (int k = 0; k < 4; ++k) acc[k] += exa * xa[k];
        } else {
            float mn = fmaxf(m, sa);
            float corr = __expf(m - mn);
            float exa = __expf(sa - mn);
            l = fmaf(l, corr, exa);
#pragma unroll
            for (int k = 0; k < 4; ++k) acc[k] = fmaf(acc[k], corr, exa * xa[k]);
            m = mn;
        }
    }

    float inv = 1.f / l;
    f32x4 bv = *reinterpret_cast<const f32x4*>(bias + c4);
    float out[4], s1 = 0.f, s2 = 0.f;
#pragma unroll
    for (int k = 0; k < 4; ++k) {
        out[k] = acc[k] * inv + bv[k];
        s1 += out[k];
        s2 += out[k] * out[k];
    }
    // LN over 256 channels: full-wave butterfly (xor 1,2,4,8,16 via swizzle; 32 via shfl)
    s1 += SWZF(s1, 0x041F); s2 += SWZF(s2, 0x041F);
    s1 += SWZF(s1, 0x081F); s2 += SWZF(s2, 0x081F);
    s1 += SWZF(s1, 0x101F); s2 += SWZF(s2, 0x101F);
    s1 += SWZF(s1, 0x201F); s2 += SWZF(s2, 0x201F);
    s1 += SWZF(s1, 0x401F); s2 += SWZF(s2, 0x401F);   // xor 16 (was missing in r3)
    s1 += __shfl_xor(s1, 32, 64);
    s2 += __shfl_xor(s2, 32, 64);
    float mu  = s1 * (1.f / 256.f);
    float var = s2 * (1.f / 256.f) - mu * mu;
    float rs  = rsqrtf(var + 1e-5f);
    f32x4 gv  = *reinterpret_cast<const f32x4*>(ln_g + c4);
    f32x4 bbv = *reinterpret_cast<const f32x4*>(ln_b + c4);
    bf16x4 o;
#pragma unroll
    for (int k = 0; k < 4; ++k) {
        float y = (out[k] - mu) * rs * gv[k] + bbv[k];
        y = y > 0.f ? y : expm1f(y);                    // ELU
        o[k] = f2b(y);
    }
    *reinterpret_cast<bf16x4*>(hout + (long)i * 256 + c4) = o;
}

// ---------------- launch ----------------
extern "C" void kernel_launch(void* const* d_in, const int* in_sizes, int n_in,
                              void* d_out, int out_size, void* d_ws, size_t ws_size,
                              hipStream_t stream) {
    const float* x    = (const float*)d_in[0];
    const int*   ei   = (const int*)d_in[1];
    const float* Wl1  = (const float*)d_in[2];
    const float* Wr1  = (const float*)d_in[3];
    const float* att1 = (const float*)d_in[4];
    const float* b1   = (const float*)d_in[5];
    const float* ln1g = (const float*)d_in[6];
    const float* ln1b = (const float*)d_in[7];
    const float* Wl2  = (const float*)d_in[8];
    const float* Wr2  = (const float*)d_in[9];
    const float* att2 = (const float*)d_in[10];
    const float* b2   = (const float*)d_in[11];
    const float* ln2g = (const float*)d_in[12];
    const float* ln2b = (const float*)d_in[13];
    const float* Wmu  = (const float*)d_in[14];
    const float* bmu  = (const float*)d_in[15];
    const float* Wlv  = (const float*)d_in[16];
    const float* blv  = (const float*)d_in[17];

    // workspace layout
    short* bufXL = (short*)d_ws;                       // [N,512] bf16 (xl|xr)
    short* bufH  = bufXL + (long)NN * 512;             // [N,256] bf16 (xb / h)
    short* Wb1t  = bufH + (long)NN * 256;              // 512*256
    short* Wb2t  = Wb1t + 512 * 256;
    short* Wb3t  = Wb2t + 512 * 256;                   // 128*256
    float* bias3 = (float*)(Wb3t + 128 * 256);         // 128
    int* counts  = (int*)(bias3 + 128);
    int* offsets = counts + NN;                        // N+1
    int* cursor  = offsets + NN + 1;
    int* csr_src = cursor + NN;                        // E

    const int* src = ei;
    const int* dst = ei + NE;

    // CSR by dst
    hipMemsetAsync(counts, 0, NN * sizeof(int), stream);
    hist_kernel<<<(NE + 255) / 256, 256, 0, stream>>>(dst, counts);
    scan_kernel<<<1, 256, 0, stream>>>(counts, offsets, cursor);
    scatter_kernel<<<(NE + 255) / 256, 256, 0, stream>>>(src, dst, cursor, csr_src);

    // prep: x -> bf16, pack transposed weights
    cvt_x_kernel<<<(NN * HCn) / (8 * 256), 256, 0, stream>>>(x, bufH);
    pack_w_kernel<<<1153, 256, 0, stream>>>(Wl1, Wr1, Wl2, Wr2, Wmu, Wlv, bmu, blv,
                                            Wb1t, Wb2t, Wb3t, bias3);

    const int GM = (NN + 127) / 128;   // 391
    dim3 g1(GM, 8);                    // Nc=512
    dim3 g3(GM, 2);                    // Nc=128

    // layer 1
    gemm_k<0><<<g1, 256, 0, stream>>>(bufH, Wb1t, bufXL, nullptr, 512);
    gat_node_kernel<<<NN / 4, 256, 0, stream>>>(bufXL, offsets, csr_src,
                                                att1, b1, ln1g, ln1b, bufH);
    // layer 2
    gemm_k<0><<<g1, 256, 0, stream>>>(bufH, Wb2t, bufXL, nullptr, 512);
    gat_node_kernel<<<NN / 4, 256, 0, stream>>>(bufXL, offsets, csr_src,
                                                att2, b2, ln2g, ln2b, bufH);
    // heads: [mu|logvar]
    gemm_k<1><<<g3, 256, 0, stream>>>(bufH, Wb3t, d_out, bias3, 128);
}

// Round 5
// 386.312 us; speedup vs baseline: 2.6249x; 1.2915x over previous
//
#include <hip/hip_runtime.h>
#include <hip/hip_bf16.h>

#define NN 50000
#define NE 800000
#define HCn 256
#define LATn 64

typedef short bf16x4 __attribute__((ext_vector_type(4)));
typedef short bf16x8 __attribute__((ext_vector_type(8)));
typedef float f32x4 __attribute__((ext_vector_type(4)));

__device__ __forceinline__ short f2b(float f) {
    __hip_bfloat16 h = __float2bfloat16(f);   // RNE
    return __builtin_bit_cast(short, h);
}
__device__ __forceinline__ float b2f(short s) {
    return __bfloat162float(__builtin_bit_cast(__hip_bfloat16, s));
}

// single-instruction lane swizzle (BitMode xor; works within 32-lane halves)
#define SWZF(v, pat) __builtin_bit_cast(float, __builtin_amdgcn_ds_swizzle(__builtin_bit_cast(int, v), pat))

// ---------------- CSR build ----------------
__global__ void hist_kernel(const int* __restrict__ dst, int* __restrict__ counts) {
    int e = blockIdx.x * 256 + threadIdx.x;
    if (e < NE) atomicAdd(&counts[dst[e]], 1);
}

// phase 1: in-place block-local exclusive scan of counts; emit block sums
__global__ __launch_bounds__(1024) void scan1_kernel(int* __restrict__ counts,
                                                     int* __restrict__ blocksum) {
    const int g = blockIdx.x * 1024 + threadIdx.x;
    const int lane = threadIdx.x & 63;
    const int wv = threadIdx.x >> 6;            // 0..15
    int v = (g < NN) ? counts[g] : 0;
    int s = v;
#pragma unroll
    for (int d = 1; d < 64; d <<= 1) {
        int t = __shfl_up(s, d, 64);
        if (lane >= d) s += t;
    }
    __shared__ int wsum[16];
    if (lane == 63) wsum[wv] = s;
    __syncthreads();
    if (threadIdx.x == 0) {
        int run = 0;
#pragma unroll
        for (int q = 0; q < 16; ++q) { int t = wsum[q]; wsum[q] = run; run += t; }
        blocksum[blockIdx.x] = run;
    }
    __syncthreads();
    int excl = s - v + wsum[wv];
    if (g < NN) counts[g] = excl;
}

// phase 2: exclusive scan of 49 block sums (one wave); also offsets[NN] = NE
__global__ void scan2_kernel(int* __restrict__ blocksum, int* __restrict__ offsets, int nblk) {
    const int lane = threadIdx.x;               // 64 threads
    int v = (lane < nblk) ? blocksum[lane] : 0;
    int s = v;
#pragma unroll
    for (int d = 1; d < 64; d <<= 1) {
        int t = __shfl_up(s, d, 64);
        if (lane >= d) s += t;
    }
    if (lane < nblk) blocksum[lane] = s - v;    // exclusive
    if (lane == 0) offsets[NN] = NE;
}

// phase 3: add block base, write offsets and cursor
__global__ __launch_bounds__(1024) void scan3_kernel(const int* __restrict__ counts,
                                                     const int* __restrict__ blocksum,
                                                     int* __restrict__ offsets,
                                                     int* __restrict__ cursor) {
    const int g = blockIdx.x * 1024 + threadIdx.x;
    if (g < NN) {
        int v = counts[g] + blocksum[blockIdx.x];
        offsets[g] = v;
        cursor[g]  = v;
    }
}

__global__ void scatter_kernel(const int* __restrict__ src, const int* __restrict__ dst,
                               int* __restrict__ cursor, int* __restrict__ csr_src) {
    int e = blockIdx.x * 256 + threadIdx.x;
    if (e < NE) {
        int p = atomicAdd(&cursor[dst[e]], 1);
        csr_src[p] = src[e];
    }
}

// ---------------- f32 -> bf16 convert (x) ----------------
__global__ __launch_bounds__(256) void cvt_x_kernel(const float* __restrict__ x,
                                                    short* __restrict__ xb) {
    long i = ((long)blockIdx.x * 256 + threadIdx.x) * 8;
    const f32x4* p = reinterpret_cast<const f32x4*>(x + i);
    f32x4 a = p[0], b = p[1];
    bf16x8 o;
#pragma unroll
    for (int j = 0; j < 4; ++j) { o[j] = f2b(a[j]); o[4 + j] = f2b(b[j]); }
    *reinterpret_cast<bf16x8*>(xb + i) = o;
}

// ---------------- pack weights to bf16, TRANSPOSED: Wbt[n][k] = W[k][n] ----------------
__global__ void pack_w_kernel(const float* __restrict__ Wl1, const float* __restrict__ Wr1,
                              const float* __restrict__ Wl2, const float* __restrict__ Wr2,
                              const float* __restrict__ Wmu, const float* __restrict__ Wlv,
                              const float* __restrict__ bmu, const float* __restrict__ blv,
                              short* __restrict__ Wb1t, short* __restrict__ Wb2t,
                              short* __restrict__ Wb3t, float* __restrict__ bias3) {
    int i = blockIdx.x * 256 + threadIdx.x;
    const int S1 = 512 * 256, S2 = 2 * S1, S3 = S2 + 128 * 256;
    if (i < S1) {
        int c = i >> 8, k = i & 255;
        float v = (c < 256) ? Wl1[k * 256 + c] : Wr1[k * 256 + (c - 256)];
        Wb1t[i] = f2b(v);
    } else if (i < S2) {
        int j = i - S1; int c = j >> 8, k = j & 255;
        float v = (c < 256) ? Wl2[k * 256 + c] : Wr2[k * 256 + (c - 256)];
        Wb2t[j] = f2b(v);
    } else if (i < S3) {
        int j = i - S2; int c = j >> 8, k = j & 255;
        float v = (c < 64) ? Wmu[k * 64 + c] : Wlv[k * 64 + (c - 64)];
        Wb3t[j] = f2b(v);
    } else if (i < S3 + 128) {
        int c = i - S3;
        bias3[c] = (c < 64) ? bmu[c] : blv[c - 64];
    }
}

// ---------------- GEMM: out[M,Nc] = A[M,256] @ W[256,Nc], W given transposed Wbt[Nc,256] ----------------
// 128x64 tile, 4 waves; B panel staged once in LDS via b128 writes; A frags direct from global.
template<int OUT_MODE>   // 0: bf16 out, row-stride Nc | 1: f32 out split 64|64 + bias
__global__ __launch_bounds__(256) void gemm_k(
    const short* __restrict__ A, const short* __restrict__ Wbt,
    void* __restrict__ outp, const float* __restrict__ bias, int Nc)
{
    __shared__ short Bs[64 * 264];   // [n][k], stride 264
    const int t = threadIdx.x;
    const int w = t >> 6, lane = t & 63;
    const int row0 = blockIdx.x * 128, col0 = blockIdx.y * 64;

    // stage B panel once: Bs[n][k] = Wbt[col0+n][k]  (coalesced load, b128 LDS write)
    {
        const int sn = t >> 2;            // 0..63
        const int sk0 = (t & 3) * 8;      // 0,8,16,24
        const short* wp = Wbt + (long)(col0 + sn) * 256 + sk0;
#pragma unroll
        for (int r = 0; r < 8; ++r) {
            int k = r * 32 + sk0;
            bf16x8 v = *reinterpret_cast<const bf16x8*>(wp + r * 32);
            *reinterpret_cast<bf16x8*>(&Bs[sn * 264 + k]) = v;
        }
    }
    __syncthreads();

    f32x4 acc[2][4];
#pragma unroll
    for (int a = 0; a < 2; ++a)
#pragma unroll
        for (int b = 0; b < 4; ++b) acc[a][b] = (f32x4){0.f, 0.f, 0.f, 0.f};

    const int arow = lane & 15, kq = lane >> 4;
    int r0 = row0 + w * 32 + arow;      if (r0 > NN - 1) r0 = NN - 1;
    int r1 = row0 + w * 32 + 16 + arow; if (r1 > NN - 1) r1 = NN - 1;
    const short* pa0 = A + (long)r0 * 256 + kq * 8;
    const short* pa1 = A + (long)r1 * 256 + kq * 8;

#pragma unroll
    for (int k0 = 0; k0 < 256; k0 += 32) {
        bf16x8 a0 = *reinterpret_cast<const bf16x8*>(pa0 + k0);
        bf16x8 a1 = *reinterpret_cast<const bf16x8*>(pa1 + k0);
#pragma unroll
        for (int nt = 0; nt < 4; ++nt) {
            bf16x8 b = *reinterpret_cast<const bf16x8*>(&Bs[(nt * 16 + arow) * 264 + k0 + kq * 8]);
            acc[0][nt] = __builtin_amdgcn_mfma_f32_16x16x32_bf16(a0, b, acc[0][nt], 0, 0, 0);
            acc[1][nt] = __builtin_amdgcn_mfma_f32_16x16x32_bf16(a1, b, acc[1][nt], 0, 0, 0);
        }
    }

    // epilogue: C/D layout col = lane&15, row = (lane>>4)*4 + r
#pragma unroll
    for (int rb = 0; rb < 2; ++rb)
#pragma unroll
        for (int nt = 0; nt < 4; ++nt) {
            int gcol = col0 + nt * 16 + arow;
#pragma unroll
            for (int r = 0; r < 4; ++r) {
                int grow = row0 + w * 32 + rb * 16 + kq * 4 + r;
                if (grow < NN) {
                    float v = acc[rb][nt][r];
                    if (OUT_MODE == 0) {
                        ((short*)outp)[(long)grow * Nc + gcol] = f2b(v);
                    } else {
                        v += bias[gcol];
                        float* o = (float*)outp;
                        if (gcol < 64) o[(long)grow * 64 + gcol] = v;
                        else           o[(long)NN * 64 + (long)grow * 64 + (gcol - 64)] = v;
                    }
                }
            }
        }
}

// ---------------- fused GATv2: one WAVE per node, 4x16-lane head groups ----------------
// xlr: [N,512] bf16 (cols 0..255 = xl, cols 256..511 = xr)
__device__ __forceinline__ void edge_score(const short* __restrict__ xlr, int j, int c4,
                                           const float* xr, const f32x4& attv,
                                           float* xf, float& s) {
    bf16x4 v = *reinterpret_cast<const bf16x4*>(xlr + (long)j * 512 + c4);
    s = 0.f;
#pragma unroll
    for (int k = 0; k < 4; ++k) {
        xf[k] = b2f(v[k]);
        float val = xf[k] + xr[k];
        val = fmaxf(val, 0.2f * val);               // leaky_relu(0.2)
        s = fmaf(val, attv[k], s);
    }
    // 16-lane head-group reduce: xor 1,2,4,8
    s += SWZF(s, 0x041F);
    s += SWZF(s, 0x081F);
    s += SWZF(s, 0x101F);
    s += SWZF(s, 0x201F);
}

__global__ __launch_bounds__(256) void gat_node_kernel(
    const short* __restrict__ xlr,
    const int* __restrict__ offsets, const int* __restrict__ csr_src,
    const float* __restrict__ att, const float* __restrict__ bias,
    const float* __restrict__ ln_g, const float* __restrict__ ln_b,
    short* __restrict__ hout)
{
    const int i = blockIdx.x * 4 + (threadIdx.x >> 6);
    const int lane = threadIdx.x & 63;
    const int c4 = (lane >> 4) * 64 + (lane & 15) * 4;   // head*64 + 4 channels

    f32x4 attv = *reinterpret_cast<const f32x4*>(att + c4);
    float xr[4];
    {
        bf16x4 v = *reinterpret_cast<const bf16x4*>(xlr + (long)i * 512 + 256 + c4);
#pragma unroll
        for (int k = 0; k < 4; ++k) xr[k] = b2f(v[k]);
    }

    float m, l;
    float acc[4];
    // self loop first: alpha-unnorm = 1, m = s_self
    {
        float xf[4], s;
        edge_score(xlr, i, c4, xr, attv, xf, s);
        m = s; l = 1.f;
#pragma unroll
        for (int k = 0; k < 4; ++k) acc[k] = xf[k];
    }

    const int p0 = offsets[i], p1 = offsets[i + 1];
    int p = p0;
    for (; p + 2 <= p1; p += 2) {
        int ja = __builtin_amdgcn_readfirstlane(csr_src[p]);
        int jb = __builtin_amdgcn_readfirstlane(csr_src[p + 1]);
        float xa[4], xb[4], sa, sb;
        edge_score(xlr, ja, c4, xr, attv, xa, sa);
        edge_score(xlr, jb, c4, xr, attv, xb, sb);
        float sm = fmaxf(sa, sb);
        if (__all(sm <= m + 4.f)) {
            // defer-max: keep m, no rescale (values bounded by e^4)
            float exa = __expf(sa - m), exb = __expf(sb - m);
            l += exa + exb;
#pragma unroll
            for (int k = 0; k < 4; ++k)
                acc[k] += exa * xa[k] + exb * xb[k];
        } else {
            float mn = fmaxf(m, sm);
            float corr = __expf(m - mn);
            float exa = __expf(sa - mn), exb = __expf(sb - mn);
            l = fmaf(l, corr, exa + exb);
#pragma unroll
            for (int k = 0; k < 4; ++k)
                acc[k] = fmaf(acc[k], corr, exa * xa[k] + exb * xb[k]);
            m = mn;
        }
    }
    if (p < p1) {
        int ja = __builtin_amdgcn_readfirstlane(csr_src[p]);
        float xa[4], sa;
        edge_score(xlr, ja, c4, xr, attv, xa, sa);
        if (__all(sa <= m + 4.f)) {
            float exa = __expf(sa - m);
            l += exa;
#pragma unroll
            for (int k = 0; k < 4; ++k) acc[k] += exa * xa[k];
        } else {
            float mn = fmaxf(m, sa);
            float corr = __expf(m - mn);
            float exa = __expf(sa - mn);
            l = fmaf(l, corr, exa);
#pragma unroll
            for (int k = 0; k < 4; ++k) acc[k] = fmaf(acc[k], corr, exa * xa[k]);
            m = mn;
        }
    }

    float inv = 1.f / l;
    f32x4 bv = *reinterpret_cast<const f32x4*>(bias + c4);
    float out[4], s1 = 0.f, s2 = 0.f;
#pragma unroll
    for (int k = 0; k < 4; ++k) {
        out[k] = acc[k] * inv + bv[k];
        s1 += out[k];
        s2 += out[k] * out[k];
    }
    // LN over 256 channels: full-wave butterfly (xor 1,2,4,8,16 via swizzle; 32 via shfl)
    s1 += SWZF(s1, 0x041F); s2 += SWZF(s2, 0x041F);
    s1 += SWZF(s1, 0x081F); s2 += SWZF(s2, 0x081F);
    s1 += SWZF(s1, 0x101F); s2 += SWZF(s2, 0x101F);
    s1 += SWZF(s1, 0x201F); s2 += SWZF(s2, 0x201F);
    s1 += SWZF(s1, 0x401F); s2 += SWZF(s2, 0x401F);   // xor 16
    s1 += __shfl_xor(s1, 32, 64);
    s2 += __shfl_xor(s2, 32, 64);
    float mu  = s1 * (1.f / 256.f);
    float var = s2 * (1.f / 256.f) - mu * mu;
    float rs  = rsqrtf(var + 1e-5f);
    f32x4 gv  = *reinterpret_cast<const f32x4*>(ln_g + c4);
    f32x4 bbv = *reinterpret_cast<const f32x4*>(ln_b + c4);
    bf16x4 o;
#pragma unroll
    for (int k = 0; k < 4; ++k) {
        float y = (out[k] - mu) * rs * gv[k] + bbv[k];
        y = y > 0.f ? y : expm1f(y);                    // ELU
        o[k] = f2b(y);
    }
    *reinterpret_cast<bf16x4*>(hout + (long)i * 256 + c4) = o;
}

// ---------------- launch ----------------
extern "C" void kernel_launch(void* const* d_in, const int* in_sizes, int n_in,
                              void* d_out, int out_size, void* d_ws, size_t ws_size,
                              hipStream_t stream) {
    const float* x    = (const float*)d_in[0];
    const int*   ei   = (const int*)d_in[1];
    const float* Wl1  = (const float*)d_in[2];
    const float* Wr1  = (const float*)d_in[3];
    const float* att1 = (const float*)d_in[4];
    const float* b1   = (const float*)d_in[5];
    const float* ln1g = (const float*)d_in[6];
    const float* ln1b = (const float*)d_in[7];
    const float* Wl2  = (const float*)d_in[8];
    const float* Wr2  = (const float*)d_in[9];
    const float* att2 = (const float*)d_in[10];
    const float* b2   = (const float*)d_in[11];
    const float* ln2g = (const float*)d_in[12];
    const float* ln2b = (const float*)d_in[13];
    const float* Wmu  = (const float*)d_in[14];
    const float* bmu  = (const float*)d_in[15];
    const float* Wlv  = (const float*)d_in[16];
    const float* blv  = (const float*)d_in[17];

    // workspace layout
    short* bufXL = (short*)d_ws;                       // [N,512] bf16 (xl|xr)
    short* bufH  = bufXL + (long)NN * 512;             // [N,256] bf16 (xb / h)
    short* Wb1t  = bufH + (long)NN * 256;              // 512*256
    short* Wb2t  = Wb1t + 512 * 256;
    short* Wb3t  = Wb2t + 512 * 256;                   // 128*256
    float* bias3 = (float*)(Wb3t + 128 * 256);         // 128
    int* counts  = (int*)(bias3 + 128);
    int* offsets = counts + NN;                        // N+1
    int* cursor  = offsets + NN + 1;
    int* csr_src = cursor + NN;                        // E
    int* blocksum = csr_src + NE;                      // 64

    const int* src = ei;
    const int* dst = ei + NE;

    const int NBLK = (NN + 1023) / 1024;               // 49

    // CSR by dst (parallel scan)
    hipMemsetAsync(counts, 0, NN * sizeof(int), stream);
    hist_kernel<<<(NE + 255) / 256, 256, 0, stream>>>(dst, counts);
    scan1_kernel<<<NBLK, 1024, 0, stream>>>(counts, blocksum);
    scan2_kernel<<<1, 64, 0, stream>>>(blocksum, offsets, NBLK);
    scan3_kernel<<<NBLK, 1024, 0, stream>>>(counts, blocksum, offsets, cursor);
    scatter_kernel<<<(NE + 255) / 256, 256, 0, stream>>>(src, dst, cursor, csr_src);

    // prep: x -> bf16, pack transposed weights
    cvt_x_kernel<<<(NN * HCn) / (8 * 256), 256, 0, stream>>>(x, bufH);
    pack_w_kernel<<<1153, 256, 0, stream>>>(Wl1, Wr1, Wl2, Wr2, Wmu, Wlv, bmu, blv,
                                            Wb1t, Wb2t, Wb3t, bias3);

    const int GM = (NN + 127) / 128;   // 391
    dim3 g1(GM, 8);                    // Nc=512
    dim3 g3(GM, 2);                    // Nc=128

    // layer 1
    gemm_k<0><<<g1, 256, 0, stream>>>(bufH, Wb1t, bufXL, nullptr, 512);
    gat_node_kernel<<<NN / 4, 256, 0, stream>>>(bufXL, offsets, csr_src,
                                                att1, b1, ln1g, ln1b, bufH);
    // layer 2
    gemm_k<0><<<g1, 256, 0, stream>>>(bufH, Wb2t, bufXL, nullptr, 512);
    gat_node_kernel<<<NN / 4, 256, 0, stream>>>(bufXL, offsets, csr_src,
                                                att2, b2, ln2g, ln2b, bufH);
    // heads: [mu|logvar]
    gemm_k<1><<<g3, 256, 0, stream>>>(bufH, Wb3t, d_out, bias3, 128);
}

// Round 6
// 380.553 us; speedup vs baseline: 2.6646x; 1.0151x over previous
//
#include <hip/hip_runtime.h>
#include <hip/hip_bf16.h>

#define NN 50000
#define NE 800000
#define HCn 256
#define LATn 64

typedef short bf16x4 __attribute__((ext_vector_type(4)));
typedef short bf16x8 __attribute__((ext_vector_type(8)));
typedef float f32x4 __attribute__((ext_vector_type(4)));

__device__ __forceinline__ short f2b(float f) {
    __hip_bfloat16 h = __float2bfloat16(f);   // RNE
    return __builtin_bit_cast(short, h);
}
__device__ __forceinline__ float b2f(short s) {
    return __bfloat162float(__builtin_bit_cast(__hip_bfloat16, s));
}

// single-instruction lane swizzle (BitMode xor; works within 32-lane halves)
#define SWZF(v, pat) __builtin_bit_cast(float, __builtin_amdgcn_ds_swizzle(__builtin_bit_cast(int, v), pat))

#define C04L2E 0.5770780163555854f   // 0.4 * log2(e)
#define C06L2E 0.8656170245333781f   // 0.6 * log2(e)
#define DEFER_THR 8.0f               // defer-max threshold (log2 units)

// ---------------- CSR build ----------------
__global__ void hist_kernel(const int* __restrict__ dst, int* __restrict__ counts) {
    int e = blockIdx.x * 256 + threadIdx.x;
    if (e < NE) atomicAdd(&counts[dst[e]], 1);
}

// phase 1: in-place block-local exclusive scan of counts; emit block sums
__global__ __launch_bounds__(1024) void scan1_kernel(int* __restrict__ counts,
                                                     int* __restrict__ blocksum) {
    const int g = blockIdx.x * 1024 + threadIdx.x;
    const int lane = threadIdx.x & 63;
    const int wv = threadIdx.x >> 6;            // 0..15
    int v = (g < NN) ? counts[g] : 0;
    int s = v;
#pragma unroll
    for (int d = 1; d < 64; d <<= 1) {
        int t = __shfl_up(s, d, 64);
        if (lane >= d) s += t;
    }
    __shared__ int wsum[16];
    if (lane == 63) wsum[wv] = s;
    __syncthreads();
    if (threadIdx.x == 0) {
        int run = 0;
#pragma unroll
        for (int q = 0; q < 16; ++q) { int t = wsum[q]; wsum[q] = run; run += t; }
        blocksum[blockIdx.x] = run;
    }
    __syncthreads();
    int excl = s - v + wsum[wv];
    if (g < NN) counts[g] = excl;
}

// phase 2: exclusive scan of block sums (one wave); also offsets[NN] = NE
__global__ void scan2_kernel(int* __restrict__ blocksum, int* __restrict__ offsets, int nblk) {
    const int lane = threadIdx.x;               // 64 threads
    int v = (lane < nblk) ? blocksum[lane] : 0;
    int s = v;
#pragma unroll
    for (int d = 1; d < 64; d <<= 1) {
        int t = __shfl_up(s, d, 64);
        if (lane >= d) s += t;
    }
    if (lane < nblk) blocksum[lane] = s - v;    // exclusive
    if (lane == 0) offsets[NN] = NE;
}

// phase 3: add block base, write offsets and cursor
__global__ __launch_bounds__(1024) void scan3_kernel(const int* __restrict__ counts,
                                                     const int* __restrict__ blocksum,
                                                     int* __restrict__ offsets,
                                                     int* __restrict__ cursor) {
    const int g = blockIdx.x * 1024 + threadIdx.x;
    if (g < NN) {
        int v = counts[g] + blocksum[blockIdx.x];
        offsets[g] = v;
        cursor[g]  = v;
    }
}

__global__ void scatter_kernel(const int* __restrict__ src, const int* __restrict__ dst,
                               int* __restrict__ cursor, int* __restrict__ csr_src) {
    int e = blockIdx.x * 256 + threadIdx.x;
    if (e < NE) {
        int p = atomicAdd(&cursor[dst[e]], 1);
        csr_src[p] = src[e];
    }
}

// ---------------- f32 -> bf16 convert (x) ----------------
__global__ __launch_bounds__(256) void cvt_x_kernel(const float* __restrict__ x,
                                                    short* __restrict__ xb) {
    long i = ((long)blockIdx.x * 256 + threadIdx.x) * 8;
    const f32x4* p = reinterpret_cast<const f32x4*>(x + i);
    f32x4 a = p[0], b = p[1];
    bf16x8 o;
#pragma unroll
    for (int j = 0; j < 4; ++j) { o[j] = f2b(a[j]); o[4 + j] = f2b(b[j]); }
    *reinterpret_cast<bf16x8*>(xb + i) = o;
}

// ---------------- pack weights to bf16, TRANSPOSED: Wbt[n][k] = W[k][n] ----------------
__global__ void pack_w_kernel(const float* __restrict__ Wl1, const float* __restrict__ Wr1,
                              const float* __restrict__ Wl2, const float* __restrict__ Wr2,
                              const float* __restrict__ Wmu, const float* __restrict__ Wlv,
                              const float* __restrict__ bmu, const float* __restrict__ blv,
                              short* __restrict__ Wb1t, short* __restrict__ Wb2t,
                              short* __restrict__ Wb3t, float* __restrict__ bias3) {
    int i = blockIdx.x * 256 + threadIdx.x;
    const int S1 = 512 * 256, S2 = 2 * S1, S3 = S2 + 128 * 256;
    if (i < S1) {
        int c = i >> 8, k = i & 255;
        float v = (c < 256) ? Wl1[k * 256 + c] : Wr1[k * 256 + (c - 256)];
        Wb1t[i] = f2b(v);
    } else if (i < S2) {
        int j = i - S1; int c = j >> 8, k = j & 255;
        float v = (c < 256) ? Wl2[k * 256 + c] : Wr2[k * 256 + (c - 256)];
        Wb2t[j] = f2b(v);
    } else if (i < S3) {
        int j = i - S2; int c = j >> 8, k = j & 255;
        float v = (c < 64) ? Wmu[k * 64 + c] : Wlv[k * 64 + (c - 64)];
        Wb3t[j] = f2b(v);
    } else if (i < S3 + 128) {
        int c = i - S3;
        bias3[c] = (c < 64) ? bmu[c] : blv[c - 64];
    }
}

// ---------------- GEMM: out[M,Nc] = A[M,256] @ W[256,Nc], W given transposed Wbt[Nc,256] ----------------
template<int OUT_MODE>   // 0: bf16 out, row-stride Nc | 1: f32 out split 64|64 + bias
__global__ __launch_bounds__(256) void gemm_k(
    const short* __restrict__ A, const short* __restrict__ Wbt,
    void* __restrict__ outp, const float* __restrict__ bias, int Nc)
{
    __shared__ short Bs[64 * 264];   // [n][k], stride 264
    const int t = threadIdx.x;
    const int w = t >> 6, lane = t & 63;
    const int row0 = blockIdx.x * 128, col0 = blockIdx.y * 64;

    // stage B panel once: Bs[n][k] = Wbt[col0+n][k]
    {
        const int sn = t >> 2;            // 0..63
        const int sk0 = (t & 3) * 8;      // 0,8,16,24
        const short* wp = Wbt + (long)(col0 + sn) * 256 + sk0;
#pragma unroll
        for (int r = 0; r < 8; ++r) {
            int k = r * 32 + sk0;
            bf16x8 v = *reinterpret_cast<const bf16x8*>(wp + r * 32);
            *reinterpret_cast<bf16x8*>(&Bs[sn * 264 + k]) = v;
        }
    }
    __syncthreads();

    f32x4 acc[2][4];
#pragma unroll
    for (int a = 0; a < 2; ++a)
#pragma unroll
        for (int b = 0; b < 4; ++b) acc[a][b] = (f32x4){0.f, 0.f, 0.f, 0.f};

    const int arow = lane & 15, kq = lane >> 4;
    int r0 = row0 + w * 32 + arow;      if (r0 > NN - 1) r0 = NN - 1;
    int r1 = row0 + w * 32 + 16 + arow; if (r1 > NN - 1) r1 = NN - 1;
    const short* pa0 = A + (long)r0 * 256 + kq * 8;
    const short* pa1 = A + (long)r1 * 256 + kq * 8;

#pragma unroll
    for (int k0 = 0; k0 < 256; k0 += 32) {
        bf16x8 a0 = *reinterpret_cast<const bf16x8*>(pa0 + k0);
        bf16x8 a1 = *reinterpret_cast<const bf16x8*>(pa1 + k0);
#pragma unroll
        for (int nt = 0; nt < 4; ++nt) {
            bf16x8 b = *reinterpret_cast<const bf16x8*>(&Bs[(nt * 16 + arow) * 264 + k0 + kq * 8]);
            acc[0][nt] = __builtin_amdgcn_mfma_f32_16x16x32_bf16(a0, b, acc[0][nt], 0, 0, 0);
            acc[1][nt] = __builtin_amdgcn_mfma_f32_16x16x32_bf16(a1, b, acc[1][nt], 0, 0, 0);
        }
    }

    // epilogue: C/D layout col = lane&15, row = (lane>>4)*4 + r
#pragma unroll
    for (int rb = 0; rb < 2; ++rb)
#pragma unroll
        for (int nt = 0; nt < 4; ++nt) {
            int gcol = col0 + nt * 16 + arow;
#pragma unroll
            for (int r = 0; r < 4; ++r) {
                int grow = row0 + w * 32 + rb * 16 + kq * 4 + r;
                if (grow < NN) {
                    float v = acc[rb][nt][r];
                    if (OUT_MODE == 0) {
                        ((short*)outp)[(long)grow * Nc + gcol] = f2b(v);
                    } else {
                        v += bias[gcol];
                        float* o = (float*)outp;
                        if (gcol < 64) o[(long)grow * 64 + gcol] = v;
                        else           o[(long)NN * 64 + (long)grow * 64 + (gcol - 64)] = v;
                    }
                }
            }
        }
}

// ---------------- att_pre: a[i][h] = 0.6*log2e * sum_c att[h][c]*xl[i][c] ----------------
__global__ __launch_bounds__(256) void att_pre_kernel(
    const short* __restrict__ xlr, const float* __restrict__ att, float* __restrict__ a)
{
    const int i = blockIdx.x * 4 + (threadIdx.x >> 6);
    const int lane = threadIdx.x & 63;
    const int c4 = (lane >> 4) * 64 + (lane & 15) * 4;
    f32x4 attv = *reinterpret_cast<const f32x4*>(att + c4);
    bf16x4 v = *reinterpret_cast<const bf16x4*>(xlr + (long)i * 512 + c4);
    float s = 0.f;
#pragma unroll
    for (int k = 0; k < 4; ++k) s = fmaf(b2f(v[k]), attv[k], s);
    s += SWZF(s, 0x041F);
    s += SWZF(s, 0x081F);
    s += SWZF(s, 0x101F);
    s += SWZF(s, 0x201F);
    if ((lane & 15) == 0) a[i * 4 + (lane >> 4)] = s * C06L2E;
}

// ---------------- fused GATv2: one WAVE per node, 4x16-lane head groups ----------------
// score (log2 domain, dst-constant term dropped): s = a[j][h] + sum_c (0.4*log2e*att_c)*|xl_jc+xr_ic|
__device__ __forceinline__ void edge_abs_score(const short* __restrict__ xlr, int j, int c4,
                                               const float* xr, const f32x4& attv04,
                                               float* xf, float& s) {
    bf16x4 v = *reinterpret_cast<const bf16x4*>(xlr + (long)j * 512 + c4);
    s = 0.f;
#pragma unroll
    for (int k = 0; k < 4; ++k) {
        xf[k] = b2f(v[k]);
        float vv = xf[k] + xr[k];
        s = fmaf(attv04[k], fabsf(vv), s);   // abs = free input modifier
    }
    s += SWZF(s, 0x041F);
    s += SWZF(s, 0x081F);
    s += SWZF(s, 0x101F);
    s += SWZF(s, 0x201F);
}

__global__ __launch_bounds__(256) void gat_node_kernel(
    const short* __restrict__ xlr, const float* __restrict__ aarr,
    const int* __restrict__ offsets, const int* __restrict__ csr_src,
    const float* __restrict__ att, const float* __restrict__ bias,
    const float* __restrict__ ln_g, const float* __restrict__ ln_b,
    short* __restrict__ hout)
{
    const int i = blockIdx.x * 4 + (threadIdx.x >> 6);
    const int lane = threadIdx.x & 63;
    const int h  = lane >> 4;
    const int c4 = h * 64 + (lane & 15) * 4;   // head*64 + 4 channels

    f32x4 attv04 = *reinterpret_cast<const f32x4*>(att + c4);
#pragma unroll
    for (int k = 0; k < 4; ++k) attv04[k] *= C04L2E;

    float xr[4];
    {
        bf16x4 v = *reinterpret_cast<const bf16x4*>(xlr + (long)i * 512 + 256 + c4);
#pragma unroll
        for (int k = 0; k < 4; ++k) xr[k] = b2f(v[k]);
    }

    float m, l;
    float acc[4];
    // self loop first
    {
        float aj = aarr[i * 4 + h];
        float xf[4], s;
        edge_abs_score(xlr, i, c4, xr, attv04, xf, s);
        m = s + aj; l = 1.f;
#pragma unroll
        for (int k = 0; k < 4; ++k) acc[k] = xf[k];
    }

    const int p0 = offsets[i], p1 = offsets[i + 1];
    int p = p0;
    for (; p + 4 <= p1; p += 4) {
        int jl = csr_src[p + (lane & 3)];       // one coalesced 16B fetch per wave
        int j0 = __builtin_amdgcn_readlane(jl, 0);
        int j1 = __builtin_amdgcn_readlane(jl, 1);
        int j2 = __builtin_amdgcn_readlane(jl, 2);
        int j3 = __builtin_amdgcn_readlane(jl, 3);
        float a0 = aarr[j0 * 4 + h], a1 = aarr[j1 * 4 + h];
        float a2 = aarr[j2 * 4 + h], a3 = aarr[j3 * 4 + h];
        float x0[4], x1[4], x2[4], x3[4], s0, s1, s2, s3;
        edge_abs_score(xlr, j0, c4, xr, attv04, x0, s0);
        edge_abs_score(xlr, j1, c4, xr, attv04, x1, s1);
        edge_abs_score(xlr, j2, c4, xr, attv04, x2, s2);
        edge_abs_score(xlr, j3, c4, xr, attv04, x3, s3);
        s0 += a0; s1 += a1; s2 += a2; s3 += a3;
        float sm = fmaxf(fmaxf(s0, s1), fmaxf(s2, s3));
        if (__all(sm <= m + DEFER_THR)) {
            float e0 = __builtin_amdgcn_exp2f(s0 - m);
            float e1 = __builtin_amdgcn_exp2f(s1 - m);
            float e2 = __builtin_amdgcn_exp2f(s2 - m);
            float e3 = __builtin_amdgcn_exp2f(s3 - m);
            l += (e0 + e1) + (e2 + e3);
#pragma unroll
            for (int k = 0; k < 4; ++k)
                acc[k] = fmaf(e0, x0[k], fmaf(e1, x1[k], fmaf(e2, x2[k], fmaf(e3, x3[k], acc[k]))));
        } else {
            float mn = fmaxf(m, sm);
            float corr = __builtin_amdgcn_exp2f(m - mn);
            float e0 = __builtin_amdgcn_exp2f(s0 - mn);
            float e1 = __builtin_amdgcn_exp2f(s1 - mn);
            float e2 = __builtin_amdgcn_exp2f(s2 - mn);
            float e3 = __builtin_amdgcn_exp2f(s3 - mn);
            l = fmaf(l, corr, (e0 + e1) + (e2 + e3));
#pragma unroll
            for (int k = 0; k < 4; ++k)
                acc[k] = fmaf(acc[k], corr,
                         fmaf(e0, x0[k], fmaf(e1, x1[k], fmaf(e2, x2[k], e3 * x3[k]))));
            m = mn;
        }
    }
    for (; p < p1; ++p) {
        int j = __builtin_amdgcn_readfirstlane(csr_src[p]);
        float aj = aarr[j * 4 + h];
        float xa[4], sa;
        edge_abs_score(xlr, j, c4, xr, attv04, xa, sa);
        sa += aj;
        if (__all(sa <= m + DEFER_THR)) {
            float ex = __builtin_amdgcn_exp2f(sa - m);
            l += ex;
#pragma unroll
            for (int k = 0; k < 4; ++k) acc[k] = fmaf(ex, xa[k], acc[k]);
        } else {
            float mn = fmaxf(m, sa);
            float corr = __builtin_amdgcn_exp2f(m - mn);
            float ex = __builtin_amdgcn_exp2f(sa - mn);
            l = fmaf(l, corr, ex);
#pragma unroll
            for (int k = 0; k < 4; ++k) acc[k] = fmaf(acc[k], corr, ex * xa[k]);
            m = mn;
        }
    }

    float inv = 1.f / l;
    f32x4 bv = *reinterpret_cast<const f32x4*>(bias + c4);
    float out[4], s1 = 0.f, s2 = 0.f;
#pragma unroll
    for (int k = 0; k < 4; ++k) {
        out[k] = acc[k] * inv + bv[k];
        s1 += out[k];
        s2 += out[k] * out[k];
    }
    // LN over 256 channels: full-wave butterfly
    s1 += SWZF(s1, 0x041F); s2 += SWZF(s2, 0x041F);
    s1 += SWZF(s1, 0x081F); s2 += SWZF(s2, 0x081F);
    s1 += SWZF(s1, 0x101F); s2 += SWZF(s2, 0x101F);
    s1 += SWZF(s1, 0x201F); s2 += SWZF(s2, 0x201F);
    s1 += SWZF(s1, 0x401F); s2 += SWZF(s2, 0x401F);   // xor 16
    s1 += __shfl_xor(s1, 32, 64);
    s2 += __shfl_xor(s2, 32, 64);
    float mu  = s1 * (1.f / 256.f);
    float var = s2 * (1.f / 256.f) - mu * mu;
    float rs  = rsqrtf(var + 1e-5f);
    f32x4 gv  = *reinterpret_cast<const f32x4*>(ln_g + c4);
    f32x4 bbv = *reinterpret_cast<const f32x4*>(ln_b + c4);
    bf16x4 o;
#pragma unroll
    for (int k = 0; k < 4; ++k) {
        float y = (out[k] - mu) * rs * gv[k] + bbv[k];
        y = y > 0.f ? y : expm1f(y);                    // ELU
        o[k] = f2b(y);
    }
    *reinterpret_cast<bf16x4*>(hout + (long)i * 256 + c4) = o;
}

// ---------------- launch ----------------
extern "C" void kernel_launch(void* const* d_in, const int* in_sizes, int n_in,
                              void* d_out, int out_size, void* d_ws, size_t ws_size,
                              hipStream_t stream) {
    const float* x    = (const float*)d_in[0];
    const int*   ei   = (const int*)d_in[1];
    const float* Wl1  = (const float*)d_in[2];
    const float* Wr1  = (const float*)d_in[3];
    const float* att1 = (const float*)d_in[4];
    const float* b1   = (const float*)d_in[5];
    const float* ln1g = (const float*)d_in[6];
    const float* ln1b = (const float*)d_in[7];
    const float* Wl2  = (const float*)d_in[8];
    const float* Wr2  = (const float*)d_in[9];
    const float* att2 = (const float*)d_in[10];
    const float* b2   = (const float*)d_in[11];
    const float* ln2g = (const float*)d_in[12];
    const float* ln2b = (const float*)d_in[13];
    const float* Wmu  = (const float*)d_in[14];
    const float* bmu  = (const float*)d_in[15];
    const float* Wlv  = (const float*)d_in[16];
    const float* blv  = (const float*)d_in[17];

    // workspace layout
    short* bufXL = (short*)d_ws;                       // [N,512] bf16 (xl|xr)
    short* bufH  = bufXL + (long)NN * 512;             // [N,256] bf16 (xb / h)
    short* Wb1t  = bufH + (long)NN * 256;              // 512*256
    short* Wb2t  = Wb1t + 512 * 256;
    short* Wb3t  = Wb2t + 512 * 256;                   // 128*256
    float* bias3 = (float*)(Wb3t + 128 * 256);         // 128
    int* counts  = (int*)(bias3 + 128);
    int* offsets = counts + NN;                        // N+1
    int* cursor  = offsets + NN + 1;
    int* csr_src = cursor + NN;                        // E
    int* blocksum = csr_src + NE;                      // 64
    float* a_arr = (float*)(blocksum + 64);            // [N,4]

    const int* src = ei;
    const int* dst = ei + NE;

    const int NBLK = (NN + 1023) / 1024;               // 49

    // CSR by dst (parallel scan)
    hipMemsetAsync(counts, 0, NN * sizeof(int), stream);
    hist_kernel<<<(NE + 255) / 256, 256, 0, stream>>>(dst, counts);
    scan1_kernel<<<NBLK, 1024, 0, stream>>>(counts, blocksum);
    scan2_kernel<<<1, 64, 0, stream>>>(blocksum, offsets, NBLK);
    scan3_kernel<<<NBLK, 1024, 0, stream>>>(counts, blocksum, offsets, cursor);
    scatter_kernel<<<(NE + 255) / 256, 256, 0, stream>>>(src, dst, cursor, csr_src);

    // prep: x -> bf16, pack transposed weights
    cvt_x_kernel<<<(NN * HCn) / (8 * 256), 256, 0, stream>>>(x, bufH);
    pack_w_kernel<<<1153, 256, 0, stream>>>(Wl1, Wr1, Wl2, Wr2, Wmu, Wlv, bmu, blv,
                                            Wb1t, Wb2t, Wb3t, bias3);

    const int GM = (NN + 127) / 128;   // 391
    dim3 g1(GM, 8);                    // Nc=512
    dim3 g3(GM, 2);                    // Nc=128

    // layer 1
    gemm_k<0><<<g1, 256, 0, stream>>>(bufH, Wb1t, bufXL, nullptr, 512);
    att_pre_kernel<<<NN / 4, 256, 0, stream>>>(bufXL, att1, a_arr);
    gat_node_kernel<<<NN / 4, 256, 0, stream>>>(bufXL, a_arr, offsets, csr_src,
                                                att1, b1, ln1g, ln1b, bufH);
    // layer 2
    gemm_k<0><<<g1, 256, 0, stream>>>(bufH, Wb2t, bufXL, nullptr, 512);
    att_pre_kernel<<<NN / 4, 256, 0, stream>>>(bufXL, att2, a_arr);
    gat_node_kernel<<<NN / 4, 256, 0, stream>>>(bufXL, a_arr, offsets, csr_src,
                                                att2, b2, ln2g, ln2b, bufH);
    // heads: [mu|logvar]
    gemm_k<1><<<g3, 256, 0, stream>>>(bufH, Wb3t, d_out, bias3, 128);
}